// Round 15
// baseline (177.666 us; speedup 1.0000x reference)
//
#include <hip/hip_runtime.h>
#include <hip/hip_bf16.h>
#include <math.h>

// N=768, H=4, D=3, HDIM=64, HID=64. e_in[i,j] = [sqn(4) | hc[j](80) | hc[i](80)]
// z0 = sqn@W0a + Bj[j] + Bi[i]  (Bi includes b0 and the hc[i] half).
// Round 15 = r9/r14 chunk wave-code VERBATIM, but 2-wave (128-thread) blocks:
// LDS/block 39.4 -> ~19.5 KB, so 8 blocks/CU fit (16 waves, 50% cap) instead
// of ~3 (36%). Per-wave tile (64 pairs) and all inner code unchanged — the
// one lever (workgroup granularity) orthogonal to the r10-r13 failures.
// Grid (6 chunks, 768 rows); partials [768][6]; finish sums 6.
//
// ws layout (float offsets):
#define WS_BJ    0         // Bj [768][64] f32
#define WS_BI    49152     // Bi [768][64] f32
#define WS_W0AT  98304     // W0a^T [64][4] f32
#define WS_BIAS  98560     // [224] f32: eb1@0, xb0@64, infb@128, 0, xb1@144, xb2@208, 0
#define WS_INFW  98784     // infw [64] f32
#define WS_WG    98848     // bf16 [224 rows][64]: W1^T@0, X0^T@64, infw@128, 0, X1^T@144, X2^T@208, 0
#define WS_PM    106016    // m_i partials [768][6][64] f32
#define WS_PS    400928    // shift partials [768][6][12] f32  (ends 456224)

typedef unsigned short ushort_t;
typedef __attribute__((ext_vector_type(8))) __bf16 bf16x8;
typedef __attribute__((ext_vector_type(4))) float f32x4;

__device__ __forceinline__ float silu_f(float v) {
    return v * __builtin_amdgcn_rcpf(1.0f + __expf(-v));
}
__device__ __forceinline__ float sigm_f(float v) {
    return __builtin_amdgcn_rcpf(1.0f + __expf(-v));
}

__device__ __forceinline__ ushort_t bf16r(float f) {
    unsigned u = __float_as_uint(f);
    u += 0x7FFFu + ((u >> 16) & 1u);
    return (ushort_t)(u >> 16);
}
__device__ __forceinline__ float bf2f(ushort_t s) { return __uint_as_float(((unsigned)s) << 16); }

__device__ __forceinline__ unsigned pk2(float a, float b) {
    __hip_bfloat162 t = __float22bfloat162_rn(make_float2(a, b));
    return *reinterpret_cast<unsigned*>(&t);
}

// ---------------- prep (256-thread blocks) ----------------
__global__ __launch_bounds__(256) void prep_kernel(
    const float* __restrict__ x, const float* __restrict__ h,
    const float* __restrict__ ew0, const float* __restrict__ eb0,
    const float* __restrict__ ew1, const float* __restrict__ eb1,
    const float* __restrict__ infw, const float* __restrict__ infb,
    const float* __restrict__ xw0, const float* __restrict__ xb0,
    const float* __restrict__ xw1, const float* __restrict__ xb1,
    const float* __restrict__ xw2, const float* __restrict__ xb2,
    float* __restrict__ ws)
{
    const int blk = blockIdx.x, tid = threadIdx.x;
    const int wv = tid >> 6, t = tid & 63;
    if (blk < 192) {
        __shared__ float hcs[4][80];
        const int m = blk * 4 + wv;
        hcs[wv][t] = h[m * 64 + t];
        if (t < 16) {
            int i2 = t >> 2, j2 = t & 3;
            float d0 = x[m*12 + j2*3 + 0] - x[m*12 + i2*3 + 0];
            float d1 = x[m*12 + j2*3 + 1] - x[m*12 + i2*3 + 1];
            float d2 = x[m*12 + j2*3 + 2] - x[m*12 + i2*3 + 2];
            hcs[wv][64 + t] = d0*d0 + d1*d1 + d2*d2;
        }
        float bj = 0.0f, bi = eb0[t];
        #pragma unroll 4
        for (int k = 0; k < 80; ++k) {
            float hv = hcs[wv][k];
            bj += hv * ew0[(4 + k) * 64 + t];
            bi += hv * ew0[(84 + k) * 64 + t];
        }
        ws[WS_BJ + m * 64 + t] = bj;
        ws[WS_BI + m * 64 + t] = bi;
    } else if (blk == 192) {
        if (wv == 0) {
            #pragma unroll
            for (int hh = 0; hh < 4; ++hh) ws[WS_W0AT + t * 4 + hh] = ew0[hh * 64 + t];
            ws[WS_INFW + t] = infw[t];
            #pragma unroll
            for (int u = 0; u < 4; ++u) {
                int idx = u * 64 + t;
                if (idx < 224) {
                    float v;
                    if (idx < 64)        v = eb1[idx];
                    else if (idx < 128)  v = xb0[idx - 64];
                    else if (idx == 128) v = infb[0];
                    else if (idx < 144)  v = 0.0f;
                    else if (idx < 208)  v = xb1[idx - 144];
                    else if (idx < 212)  v = xb2[idx - 208];
                    else                 v = 0.0f;
                    ws[WS_BIAS + idx] = v;
                }
            }
        }
    } else {
        ushort_t* wg = (ushort_t*)(ws + WS_WG);
        #pragma unroll 1
        for (int u = 0; u < 8; ++u) {
            int e = (blk - 193) * 2048 + tid * 8 + u;   // < 14336
            int r = e >> 6, k = e & 63;
            float v;
            if (r < 64)        v = ew1[k * 64 + r];
            else if (r < 128)  v = xw0[k * 64 + (r - 64)];
            else if (r == 128) v = infw[k];
            else if (r < 144)  v = 0.0f;
            else if (r < 208)  v = xw1[k * 64 + (r - 144)];
            else if (r < 212)  v = xw2[k * 4 + (r - 208)];
            else               v = 0.0f;
            wg[e] = bf16r(v);
        }
    }
}

// B-frags from per-wave LDS activations [p][k], stride 72
__device__ __forceinline__ void load_bfrags(const ushort_t* yb, int ml, int q, bf16x8 B[4][2]) {
    #pragma unroll
    for (int pt = 0; pt < 4; ++pt)
        #pragma unroll
        for (int kt = 0; kt < 2; ++kt)
            B[pt][kt] = *(const bf16x8*)(yb + (pt*16 + ml) * 72 + kt*32 + q*8);
}

template<int NMT>
__device__ __forceinline__ void gemmG(const ushort_t* __restrict__ wg, int ml, int q,
                                      const bf16x8 B[4][2], f32x4* acc) {
    #pragma unroll
    for (int mt = 0; mt < NMT; ++mt) {
        #pragma unroll
        for (int kt = 0; kt < 2; ++kt) {
            bf16x8 af = *(const bf16x8*)(wg + (mt*16 + ml) * 64 + kt*32 + q*8);
            #pragma unroll
            for (int pt = 0; pt < 4; ++pt)
                acc[mt*4 + pt] = __builtin_amdgcn_mfma_f32_16x16x32_bf16(af, B[pt][kt], acc[mt*4 + pt], 0, 0, 0);
        }
    }
}

__device__ __forceinline__ void ep_silu2(ushort_t* yb, int ml, int q,
                                         const f32x4* acc, const float* __restrict__ bias,
                                         int coff) {
    #pragma unroll
    for (int mt = 0; mt < 2; ++mt) {
        float4 bv = *(const float4*)(bias + coff + mt*16 + q*4);
        #pragma unroll
        for (int pt = 0; pt < 4; ++pt) {
            f32x4 a = acc[mt*4 + pt];
            uint2 w = make_uint2(pk2(silu_f(a[0] + bv.x), silu_f(a[1] + bv.y)),
                                 pk2(silu_f(a[2] + bv.z), silu_f(a[3] + bv.w)));
            *(uint2*)(yb + (pt*16 + ml) * 72 + coff + mt*16 + q*4) = w;
        }
    }
}

__device__ __forceinline__ void layer64(ushort_t* yb, const ushort_t* __restrict__ wg,
                                        const float* __restrict__ bias, int ml, int q) {
    bf16x8 B[4][2];
    load_bfrags(yb, ml, q, B);
    f32x4 acc[8];
    #pragma unroll
    for (int t = 0; t < 8; ++t) acc[t] = f32x4{0.f, 0.f, 0.f, 0.f};
    gemmG<2>(wg, ml, q, B, acc);
    ep_silu2(yb, ml, q, acc, bias, 0);
    #pragma unroll
    for (int t = 0; t < 8; ++t) acc[t] = f32x4{0.f, 0.f, 0.f, 0.f};
    gemmG<2>(wg + 32*64, ml, q, B, acc);
    ep_silu2(yb, ml, q, acc, bias, 32);
}

// ---------------- chunk kernel: block = (chunk it, row i), 128 pairs, 2 waves ----------------
__global__ __launch_bounds__(128, 2) void egcl_chunk(
    const float* __restrict__ x, float* __restrict__ ws)
{
    __shared__ ushort_t ybuf[2][4608];    // per-wave acts [64 p][72], 9 KB each
    __shared__ float sbuf[2][64];
    __shared__ float redm[2][64];
    __shared__ float reds[2][12];

    const int it = blockIdx.x, i = blockIdx.y, tid = threadIdx.x;
    const int wv = tid >> 6, lane = tid & 63;
    const int ml = lane & 15, q = lane >> 4;
    const int jg = it * 128 + wv * 64 + lane;

    const ushort_t* wg = (const ushort_t*)(ws + WS_WG);
    const float* bias  = ws + WS_BIAS;
    const float* infwf = ws + WS_INFW;
    ushort_t* yb = ybuf[wv];

    float xi[12];
    #pragma unroll
    for (int t = 0; t < 12; ++t) xi[t] = x[i * 12 + t];

    float sqn[4];
    {
        const float4* xp = (const float4*)(x + jg * 12);
        float4 a = xp[0], b = xp[1], c = xp[2];
        float d0, d1, d2;
        d0=a.x-xi[0]; d1=a.y-xi[1]; d2=a.z-xi[2];   sqn[0]=d0*d0+d1*d1+d2*d2;
        d0=a.w-xi[3]; d1=b.x-xi[4]; d2=b.y-xi[5];   sqn[1]=d0*d0+d1*d1+d2*d2;
        d0=b.z-xi[6]; d1=b.w-xi[7]; d2=c.x-xi[8];   sqn[2]=d0*d0+d1*d1+d2*d2;
        d0=c.y-xi[9]; d1=c.z-xi[10];d2=c.w-xi[11];  sqn[3]=d0*d0+d1*d1+d2*d2;
    }

    // ---- phi_e L0 (VALU, K=4 + Bi + Bj); write y0[p=lane][k] b128-packed ----
    {
        const float* Bi   = ws + WS_BI + i * 64;   // uniform -> s_load
        const float* w0at = ws + WS_W0AT;          // uniform -> s_load
        const float* Bj   = ws + WS_BJ + jg * 64;
        #pragma unroll
        for (int b = 0; b < 8; ++b) {
            float4 A = *(const float4*)(Bj + b*8);
            float4 Bv = *(const float4*)(Bj + b*8 + 4);
            float z[8] = {A.x, A.y, A.z, A.w, Bv.x, Bv.y, Bv.z, Bv.w};
            #pragma unroll
            for (int u = 0; u < 8; ++u) {
                int l = b*8 + u;
                float v = Bi[l] + z[u]
                        + sqn[0]*w0at[l*4+0] + sqn[1]*w0at[l*4+1]
                        + sqn[2]*w0at[l*4+2] + sqn[3]*w0at[l*4+3];
                z[u] = silu_f(v);
            }
            uint4 pkv = make_uint4(pk2(z[0],z[1]), pk2(z[2],z[3]),
                                   pk2(z[4],z[5]), pk2(z[6],z[7]));
            *(uint4*)(yb + lane * 72 + b*8) = pkv;
        }
    }

    // ---- phi_e L1: m = silu(y0 @ W1 + b1) ----
    layer64(yb, wg + 0, bias + 0, ml, q);        // m -> yb

    // ---- phi_inf VALU row-dot: s_inf[p=lane] = infb + infw . m[lane][:] ----
    {
        float sv = bias[128];
        #pragma unroll
        for (int c = 0; c < 8; ++c) {
            uint2 w0 = *(const uint2*)(yb + lane * 72 + c*8);
            uint2 w1 = *(const uint2*)(yb + lane * 72 + c*8 + 4);
            sv += __uint_as_float(w0.x << 16)          * infwf[c*8 + 0];
            sv += __uint_as_float(w0.x & 0xFFFF0000u)  * infwf[c*8 + 1];
            sv += __uint_as_float(w0.y << 16)          * infwf[c*8 + 2];
            sv += __uint_as_float(w0.y & 0xFFFF0000u)  * infwf[c*8 + 3];
            sv += __uint_as_float(w1.x << 16)          * infwf[c*8 + 4];
            sv += __uint_as_float(w1.x & 0xFFFF0000u)  * infwf[c*8 + 5];
            sv += __uint_as_float(w1.y << 16)          * infwf[c*8 + 6];
            sv += __uint_as_float(w1.y & 0xFFFF0000u)  * infwf[c*8 + 7];
        }
        sbuf[wv][lane] = (jg == i) ? 0.0f : sigm_f(sv);
    }

    // ---- m_i partial: lane=l sums e_p * m[p][l] (m still in yb) ----
    float macc = 0.0f;
    #pragma unroll 8
    for (int j2 = 0; j2 < 64; ++j2) {
        float ev = sbuf[wv][j2];
        macc += ev * bf2f(yb[j2 * 72 + lane]);
    }

    // ---- phi_x L0, L1 ----
    layer64(yb, wg + 64*64, bias + 64, ml, q);   // y1 -> yb
    layer64(yb, wg + 144*64, bias + 144, ml, q); // y2 -> yb

    // ---- phi_x L2 (64 -> 4); p overlaid into dead yb as f32 ----
    float* yf = (float*)yb;
    {
        bf16x8 B[4][2];
        load_bfrags(yb, ml, q, B);
        f32x4 acc2[4];
        #pragma unroll
        for (int t = 0; t < 4; ++t) acc2[t] = f32x4{0.f, 0.f, 0.f, 0.f};
        gemmG<1>(wg + 208*64, ml, q, B, acc2);
        if (q == 0) {
            float4 bx2 = *(const float4*)(bias + 208);
            #pragma unroll
            for (int pt = 0; pt < 4; ++pt) {
                float4 pv = make_float4(acc2[pt][0] + bx2.x, acc2[pt][1] + bx2.y,
                                        acc2[pt][2] + bx2.z, acc2[pt][3] + bx2.w);
                *(float4*)(yf + (pt*16 + ml) * 4) = pv;
            }
        }
    }

    // ---- shift contributions (lane = p); butterfly -> reds ----
    {
        float4 pv = *(const float4*)(yf + lane * 4);
        float pvh[4] = {pv.x, pv.y, pv.z, pv.w};
        float mask = (jg == i) ? 0.0f : 1.0f;
        const float4* xp = (const float4*)(x + jg * 12);
        float4 a = xp[0], b = xp[1], c = xp[2];
        float dxs[12];
        dxs[0]=a.x-xi[0]; dxs[1]=a.y-xi[1]; dxs[2]=a.z-xi[2];  dxs[3]=a.w-xi[3];
        dxs[4]=b.x-xi[4]; dxs[5]=b.y-xi[5]; dxs[6]=b.z-xi[6];  dxs[7]=b.w-xi[7];
        dxs[8]=c.x-xi[8]; dxs[9]=c.y-xi[9]; dxs[10]=c.z-xi[10];dxs[11]=c.w-xi[11];
        float s12[12];
        #pragma unroll
        for (int hh = 0; hh < 4; ++hh) {
            float nsq = (sqn[hh] == 0.0f) ? 1.0f : sqn[hh];
            float inv = mask * pvh[hh] * __builtin_amdgcn_rcpf(sqrtf(nsq) + 1.0f);
            #pragma unroll
            for (int d = 0; d < 3; ++d)
                s12[hh*3 + d] = dxs[hh*3 + d] * inv;
        }
        #pragma unroll
        for (int t = 0; t < 12; ++t) {
            float v = s12[t];
            v += __shfl_xor(v, 1, 64);
            v += __shfl_xor(v, 2, 64);
            v += __shfl_xor(v, 4, 64);
            v += __shfl_xor(v, 8, 64);
            v += __shfl_xor(v, 16, 64);
            v += __shfl_xor(v, 32, 64);
            if (lane == 0) reds[wv][t] = v;
        }
    }

    redm[wv][lane] = macc;
    __syncthreads();

    if (wv == 0) {
        ws[WS_PM + (i*6 + it)*64 + lane] = redm[0][lane] + redm[1][lane];
        if (lane < 12)
            ws[WS_PS + (i*6 + it)*12 + lane] = reds[0][lane] + reds[1][lane];
    }
}

// ---------------- finish: sum partials + phi_h + x_new (4 nodes/block) ----------------
__global__ __launch_bounds__(256) void finish_kernel(
    const float* __restrict__ x, const float* __restrict__ h,
    const float* __restrict__ hw0, const float* __restrict__ hb0,
    const float* __restrict__ hw1, const float* __restrict__ hb1,
    const float* __restrict__ hw2, const float* __restrict__ hb2,
    const float* __restrict__ ws, float* __restrict__ out)
{
    __shared__ float inbuf[4][128];
    __shared__ float zbuf[4][64];
    const int tid = threadIdx.x;
    const int wv = tid >> 6, lane = tid & 63;
    const int i = blockIdx.x * 4 + wv;

    const float* pm = ws + WS_PM + i*6*64;
    float mi = ((pm[lane] + pm[64 + lane]) + (pm[128 + lane] + pm[192 + lane])
              + (pm[256 + lane] + pm[320 + lane])) * (1.0f / sqrtf(767.0f));
    inbuf[wv][lane] = mi;
    inbuf[wv][64 + lane] = h[i*64 + lane];

    if (lane < 12) {
        const float* ps = ws + WS_PS + i*6*12;
        float sh = ((ps[lane] + ps[12 + lane]) + (ps[24 + lane] + ps[36 + lane]))
                 + (ps[48 + lane] + ps[60 + lane]);
        out[i*12 + lane] = x[i*12 + lane] + sh * (1.0f / 767.0f);
    }

    // single wave per node: LDS ops in-order, no barrier needed
    float a = hb0[lane];
    #pragma unroll 8
    for (int k = 0; k < 128; ++k) a += inbuf[wv][k] * hw0[k*64 + lane];
    zbuf[wv][lane] = silu_f(a);

    a = hb1[lane];
    #pragma unroll 8
    for (int k = 0; k < 64; ++k) a += zbuf[wv][k] * hw1[k*64 + lane];
    zbuf[wv][lane] = silu_f(a);

    a = hb2[lane];
    #pragma unroll 8
    for (int k = 0; k < 64; ++k) a += zbuf[wv][k] * hw2[k*64 + lane];
    out[9216 + i*64 + lane] = h[i*64 + lane] + a;
}

extern "C" void kernel_launch(void* const* d_in, const int* in_sizes, int n_in,
                              void* d_out, int out_size, void* d_ws, size_t ws_size,
                              hipStream_t stream) {
    const float* x    = (const float*)d_in[0];
    const float* h    = (const float*)d_in[1];
    const float* ew0  = (const float*)d_in[2];
    const float* eb0  = (const float*)d_in[3];
    const float* ew1  = (const float*)d_in[4];
    const float* eb1  = (const float*)d_in[5];
    const float* infw = (const float*)d_in[6];
    const float* infb = (const float*)d_in[7];
    const float* xw0  = (const float*)d_in[8];
    const float* xb0  = (const float*)d_in[9];
    const float* xw1  = (const float*)d_in[10];
    const float* xb1  = (const float*)d_in[11];
    const float* xw2  = (const float*)d_in[12];
    const float* xb2  = (const float*)d_in[13];
    const float* hw0  = (const float*)d_in[14];
    const float* hb0  = (const float*)d_in[15];
    const float* hw1  = (const float*)d_in[16];
    const float* hb1  = (const float*)d_in[17];
    const float* hw2  = (const float*)d_in[18];
    const float* hb2  = (const float*)d_in[19];

    float* ws  = (float*)d_ws;
    float* out = (float*)d_out;

    prep_kernel<<<200, 256, 0, stream>>>(x, h, ew0, eb0, ew1, eb1, infw, infb,
                                         xw0, xb0, xw1, xb1, xw2, xb2, ws);
    egcl_chunk<<<dim3(6, 768), 128, 0, stream>>>(x, ws);
    finish_kernel<<<192, 256, 0, stream>>>(x, h, hw0, hb0, hw1, hb1, hw2, hb2, ws, out);
}

// Round 16
// 169.173 us; speedup vs baseline: 1.0502x; 1.0502x over previous
//
#include <hip/hip_runtime.h>
#include <hip/hip_bf16.h>
#include <math.h>

// N=768, H=4, D=3, HDIM=64, HID=64. e_in[i,j] = [sqn(4) | hc[j](80) | hc[i](80)]
// z0 = sqn@W0a + Bj[j] + Bi[i]  (Bi includes b0 and the hc[i] half).
// FINAL (= round 14): r9 chunk kernel verbatim (64 pairs/wave, grid (3,768),
// 256-thread blocks, LDS reductions) + 4-node finish blocks.
// Measured optimum: chunk 75 µs, VGPR 60, VALUBusy 68%, no spill; total ~171 µs.
// Seven structural probes all regressed: MFMA-L0 (r10, latency), 32-pair tiles
// (r11, fixed-work dup), atomics/reg-fusion (r12, spill), phi_inf fusion
// (r13, reg pressure), 2-wave blocks (r15, occupancy cap is not LDS).
//
// ws layout (float offsets):
#define WS_BJ    0         // Bj [768][64] f32
#define WS_BI    49152     // Bi [768][64] f32
#define WS_W0AT  98304     // W0a^T [64][4] f32
#define WS_BIAS  98560     // [224] f32: eb1@0, xb0@64, infb@128, 0, xb1@144, xb2@208, 0
#define WS_INFW  98784     // infw [64] f32
#define WS_WG    98848     // bf16 [224 rows][64]: W1^T@0, X0^T@64, infw@128, 0, X1^T@144, X2^T@208, 0
#define WS_PM    106016    // m_i partials [768][3][64] f32
#define WS_PS    253472    // shift partials [768][3][12] f32  (ends 281120)

typedef unsigned short ushort_t;
typedef __attribute__((ext_vector_type(8))) __bf16 bf16x8;
typedef __attribute__((ext_vector_type(4))) float f32x4;

__device__ __forceinline__ float silu_f(float v) {
    return v * __builtin_amdgcn_rcpf(1.0f + __expf(-v));
}
__device__ __forceinline__ float sigm_f(float v) {
    return __builtin_amdgcn_rcpf(1.0f + __expf(-v));
}

__device__ __forceinline__ ushort_t bf16r(float f) {
    unsigned u = __float_as_uint(f);
    u += 0x7FFFu + ((u >> 16) & 1u);
    return (ushort_t)(u >> 16);
}
__device__ __forceinline__ float bf2f(ushort_t s) { return __uint_as_float(((unsigned)s) << 16); }

__device__ __forceinline__ unsigned pk2(float a, float b) {
    __hip_bfloat162 t = __float22bfloat162_rn(make_float2(a, b));
    return *reinterpret_cast<unsigned*>(&t);
}

// ---------------- prep (256-thread blocks) ----------------
__global__ __launch_bounds__(256) void prep_kernel(
    const float* __restrict__ x, const float* __restrict__ h,
    const float* __restrict__ ew0, const float* __restrict__ eb0,
    const float* __restrict__ ew1, const float* __restrict__ eb1,
    const float* __restrict__ infw, const float* __restrict__ infb,
    const float* __restrict__ xw0, const float* __restrict__ xb0,
    const float* __restrict__ xw1, const float* __restrict__ xb1,
    const float* __restrict__ xw2, const float* __restrict__ xb2,
    float* __restrict__ ws)
{
    const int blk = blockIdx.x, tid = threadIdx.x;
    const int wv = tid >> 6, t = tid & 63;
    if (blk < 192) {
        __shared__ float hcs[4][80];
        const int m = blk * 4 + wv;
        hcs[wv][t] = h[m * 64 + t];
        if (t < 16) {
            int i2 = t >> 2, j2 = t & 3;
            float d0 = x[m*12 + j2*3 + 0] - x[m*12 + i2*3 + 0];
            float d1 = x[m*12 + j2*3 + 1] - x[m*12 + i2*3 + 1];
            float d2 = x[m*12 + j2*3 + 2] - x[m*12 + i2*3 + 2];
            hcs[wv][64 + t] = d0*d0 + d1*d1 + d2*d2;
        }
        float bj = 0.0f, bi = eb0[t];
        #pragma unroll 4
        for (int k = 0; k < 80; ++k) {
            float hv = hcs[wv][k];
            bj += hv * ew0[(4 + k) * 64 + t];
            bi += hv * ew0[(84 + k) * 64 + t];
        }
        ws[WS_BJ + m * 64 + t] = bj;
        ws[WS_BI + m * 64 + t] = bi;
    } else if (blk == 192) {
        if (wv == 0) {
            #pragma unroll
            for (int hh = 0; hh < 4; ++hh) ws[WS_W0AT + t * 4 + hh] = ew0[hh * 64 + t];
            ws[WS_INFW + t] = infw[t];
            #pragma unroll
            for (int u = 0; u < 4; ++u) {
                int idx = u * 64 + t;
                if (idx < 224) {
                    float v;
                    if (idx < 64)        v = eb1[idx];
                    else if (idx < 128)  v = xb0[idx - 64];
                    else if (idx == 128) v = infb[0];
                    else if (idx < 144)  v = 0.0f;
                    else if (idx < 208)  v = xb1[idx - 144];
                    else if (idx < 212)  v = xb2[idx - 208];
                    else                 v = 0.0f;
                    ws[WS_BIAS + idx] = v;
                }
            }
        }
    } else {
        ushort_t* wg = (ushort_t*)(ws + WS_WG);
        #pragma unroll 1
        for (int u = 0; u < 8; ++u) {
            int e = (blk - 193) * 2048 + tid * 8 + u;   // < 14336
            int r = e >> 6, k = e & 63;
            float v;
            if (r < 64)        v = ew1[k * 64 + r];
            else if (r < 128)  v = xw0[k * 64 + (r - 64)];
            else if (r == 128) v = infw[k];
            else if (r < 144)  v = 0.0f;
            else if (r < 208)  v = xw1[k * 64 + (r - 144)];
            else if (r < 212)  v = xw2[k * 4 + (r - 208)];
            else               v = 0.0f;
            wg[e] = bf16r(v);
        }
    }
}

// B-frags from per-wave LDS activations [p][k], stride 72
__device__ __forceinline__ void load_bfrags(const ushort_t* yb, int ml, int q, bf16x8 B[4][2]) {
    #pragma unroll
    for (int pt = 0; pt < 4; ++pt)
        #pragma unroll
        for (int kt = 0; kt < 2; ++kt)
            B[pt][kt] = *(const bf16x8*)(yb + (pt*16 + ml) * 72 + kt*32 + q*8);
}

template<int NMT>
__device__ __forceinline__ void gemmG(const ushort_t* __restrict__ wg, int ml, int q,
                                      const bf16x8 B[4][2], f32x4* acc) {
    #pragma unroll
    for (int mt = 0; mt < NMT; ++mt) {
        #pragma unroll
        for (int kt = 0; kt < 2; ++kt) {
            bf16x8 af = *(const bf16x8*)(wg + (mt*16 + ml) * 64 + kt*32 + q*8);
            #pragma unroll
            for (int pt = 0; pt < 4; ++pt)
                acc[mt*4 + pt] = __builtin_amdgcn_mfma_f32_16x16x32_bf16(af, B[pt][kt], acc[mt*4 + pt], 0, 0, 0);
        }
    }
}

__device__ __forceinline__ void ep_silu2(ushort_t* yb, int ml, int q,
                                         const f32x4* acc, const float* __restrict__ bias,
                                         int coff) {
    #pragma unroll
    for (int mt = 0; mt < 2; ++mt) {
        float4 bv = *(const float4*)(bias + coff + mt*16 + q*4);
        #pragma unroll
        for (int pt = 0; pt < 4; ++pt) {
            f32x4 a = acc[mt*4 + pt];
            uint2 w = make_uint2(pk2(silu_f(a[0] + bv.x), silu_f(a[1] + bv.y)),
                                 pk2(silu_f(a[2] + bv.z), silu_f(a[3] + bv.w)));
            *(uint2*)(yb + (pt*16 + ml) * 72 + coff + mt*16 + q*4) = w;
        }
    }
}

__device__ __forceinline__ void layer64(ushort_t* yb, const ushort_t* __restrict__ wg,
                                        const float* __restrict__ bias, int ml, int q) {
    bf16x8 B[4][2];
    load_bfrags(yb, ml, q, B);
    f32x4 acc[8];
    #pragma unroll
    for (int t = 0; t < 8; ++t) acc[t] = f32x4{0.f, 0.f, 0.f, 0.f};
    gemmG<2>(wg, ml, q, B, acc);
    ep_silu2(yb, ml, q, acc, bias, 0);
    #pragma unroll
    for (int t = 0; t < 8; ++t) acc[t] = f32x4{0.f, 0.f, 0.f, 0.f};
    gemmG<2>(wg + 32*64, ml, q, B, acc);
    ep_silu2(yb, ml, q, acc, bias, 32);
}

// ---------------- chunk kernel: block = (chunk it, row i), 256 pairs ----------------
__global__ __launch_bounds__(256, 2) void egcl_chunk(
    const float* __restrict__ x, float* __restrict__ ws)
{
    __shared__ ushort_t ybuf[4][4608];    // per-wave acts [64 p][72], 9 KB each
    __shared__ float sbuf[4][64];
    __shared__ float redm[4][64];
    __shared__ float reds[4][12];

    const int it = blockIdx.x, i = blockIdx.y, tid = threadIdx.x;
    const int wv = tid >> 6, lane = tid & 63;
    const int ml = lane & 15, q = lane >> 4;
    const int jg = it * 256 + wv * 64 + lane;

    const ushort_t* wg = (const ushort_t*)(ws + WS_WG);
    const float* bias  = ws + WS_BIAS;
    const float* infwf = ws + WS_INFW;
    ushort_t* yb = ybuf[wv];

    float xi[12];
    #pragma unroll
    for (int t = 0; t < 12; ++t) xi[t] = x[i * 12 + t];

    float sqn[4];
    {
        const float4* xp = (const float4*)(x + jg * 12);
        float4 a = xp[0], b = xp[1], c = xp[2];
        float d0, d1, d2;
        d0=a.x-xi[0]; d1=a.y-xi[1]; d2=a.z-xi[2];   sqn[0]=d0*d0+d1*d1+d2*d2;
        d0=a.w-xi[3]; d1=b.x-xi[4]; d2=b.y-xi[5];   sqn[1]=d0*d0+d1*d1+d2*d2;
        d0=b.z-xi[6]; d1=b.w-xi[7]; d2=c.x-xi[8];   sqn[2]=d0*d0+d1*d1+d2*d2;
        d0=c.y-xi[9]; d1=c.z-xi[10];d2=c.w-xi[11];  sqn[3]=d0*d0+d1*d1+d2*d2;
    }

    // ---- phi_e L0 (VALU, K=4 + Bi + Bj); write y0[p=lane][k] b128-packed ----
    {
        const float* Bi   = ws + WS_BI + i * 64;   // uniform -> s_load
        const float* w0at = ws + WS_W0AT;          // uniform -> s_load
        const float* Bj   = ws + WS_BJ + jg * 64;
        #pragma unroll
        for (int b = 0; b < 8; ++b) {
            float4 A = *(const float4*)(Bj + b*8);
            float4 Bv = *(const float4*)(Bj + b*8 + 4);
            float z[8] = {A.x, A.y, A.z, A.w, Bv.x, Bv.y, Bv.z, Bv.w};
            #pragma unroll
            for (int u = 0; u < 8; ++u) {
                int l = b*8 + u;
                float v = Bi[l] + z[u]
                        + sqn[0]*w0at[l*4+0] + sqn[1]*w0at[l*4+1]
                        + sqn[2]*w0at[l*4+2] + sqn[3]*w0at[l*4+3];
                z[u] = silu_f(v);
            }
            uint4 pkv = make_uint4(pk2(z[0],z[1]), pk2(z[2],z[3]),
                                   pk2(z[4],z[5]), pk2(z[6],z[7]));
            *(uint4*)(yb + lane * 72 + b*8) = pkv;
        }
    }

    // ---- phi_e L1: m = silu(y0 @ W1 + b1) ----
    layer64(yb, wg + 0, bias + 0, ml, q);        // m -> yb

    // ---- phi_inf VALU row-dot: s_inf[p=lane] = infb + infw . m[lane][:] ----
    {
        float sv = bias[128];
        #pragma unroll
        for (int c = 0; c < 8; ++c) {
            uint2 w0 = *(const uint2*)(yb + lane * 72 + c*8);
            uint2 w1 = *(const uint2*)(yb + lane * 72 + c*8 + 4);
            sv += __uint_as_float(w0.x << 16)          * infwf[c*8 + 0];
            sv += __uint_as_float(w0.x & 0xFFFF0000u)  * infwf[c*8 + 1];
            sv += __uint_as_float(w0.y << 16)          * infwf[c*8 + 2];
            sv += __uint_as_float(w0.y & 0xFFFF0000u)  * infwf[c*8 + 3];
            sv += __uint_as_float(w1.x << 16)          * infwf[c*8 + 4];
            sv += __uint_as_float(w1.x & 0xFFFF0000u)  * infwf[c*8 + 5];
            sv += __uint_as_float(w1.y << 16)          * infwf[c*8 + 6];
            sv += __uint_as_float(w1.y & 0xFFFF0000u)  * infwf[c*8 + 7];
        }
        sbuf[wv][lane] = (jg == i) ? 0.0f : sigm_f(sv);
    }

    // ---- m_i partial: lane=l sums e_p * m[p][l] (m still in yb) ----
    float macc = 0.0f;
    #pragma unroll 8
    for (int j2 = 0; j2 < 64; ++j2) {
        float ev = sbuf[wv][j2];
        macc += ev * bf2f(yb[j2 * 72 + lane]);
    }

    // ---- phi_x L0, L1 ----
    layer64(yb, wg + 64*64, bias + 64, ml, q);   // y1 -> yb
    layer64(yb, wg + 144*64, bias + 144, ml, q); // y2 -> yb

    // ---- phi_x L2 (64 -> 4); p overlaid into dead yb as f32 ----
    float* yf = (float*)yb;
    {
        bf16x8 B[4][2];
        load_bfrags(yb, ml, q, B);
        f32x4 acc2[4];
        #pragma unroll
        for (int t = 0; t < 4; ++t) acc2[t] = f32x4{0.f, 0.f, 0.f, 0.f};
        gemmG<1>(wg + 208*64, ml, q, B, acc2);
        if (q == 0) {
            float4 bx2 = *(const float4*)(bias + 208);
            #pragma unroll
            for (int pt = 0; pt < 4; ++pt) {
                float4 pv = make_float4(acc2[pt][0] + bx2.x, acc2[pt][1] + bx2.y,
                                        acc2[pt][2] + bx2.z, acc2[pt][3] + bx2.w);
                *(float4*)(yf + (pt*16 + ml) * 4) = pv;
            }
        }
    }

    // ---- shift contributions (lane = p); butterfly -> reds ----
    {
        float4 pv = *(const float4*)(yf + lane * 4);
        float pvh[4] = {pv.x, pv.y, pv.z, pv.w};
        float mask = (jg == i) ? 0.0f : 1.0f;
        const float4* xp = (const float4*)(x + jg * 12);
        float4 a = xp[0], b = xp[1], c = xp[2];
        float dxs[12];
        dxs[0]=a.x-xi[0]; dxs[1]=a.y-xi[1]; dxs[2]=a.z-xi[2];  dxs[3]=a.w-xi[3];
        dxs[4]=b.x-xi[4]; dxs[5]=b.y-xi[5]; dxs[6]=b.z-xi[6];  dxs[7]=b.w-xi[7];
        dxs[8]=c.x-xi[8]; dxs[9]=c.y-xi[9]; dxs[10]=c.z-xi[10];dxs[11]=c.w-xi[11];
        float s12[12];
        #pragma unroll
        for (int hh = 0; hh < 4; ++hh) {
            float nsq = (sqn[hh] == 0.0f) ? 1.0f : sqn[hh];
            float inv = mask * pvh[hh] * __builtin_amdgcn_rcpf(sqrtf(nsq) + 1.0f);
            #pragma unroll
            for (int d = 0; d < 3; ++d)
                s12[hh*3 + d] = dxs[hh*3 + d] * inv;
        }
        #pragma unroll
        for (int t = 0; t < 12; ++t) {
            float v = s12[t];
            v += __shfl_xor(v, 1, 64);
            v += __shfl_xor(v, 2, 64);
            v += __shfl_xor(v, 4, 64);
            v += __shfl_xor(v, 8, 64);
            v += __shfl_xor(v, 16, 64);
            v += __shfl_xor(v, 32, 64);
            if (lane == 0) reds[wv][t] = v;
        }
    }

    redm[wv][lane] = macc;
    __syncthreads();

    if (wv == 0) {
        ws[WS_PM + (i*3 + it)*64 + lane] =
            redm[0][lane] + redm[1][lane] + redm[2][lane] + redm[3][lane];
        if (lane < 12)
            ws[WS_PS + (i*3 + it)*12 + lane] =
                reds[0][lane] + reds[1][lane] + reds[2][lane] + reds[3][lane];
    }
}

// ---------------- finish: sum partials + phi_h + x_new (4 nodes/block) ----------------
__global__ __launch_bounds__(256) void finish_kernel(
    const float* __restrict__ x, const float* __restrict__ h,
    const float* __restrict__ hw0, const float* __restrict__ hb0,
    const float* __restrict__ hw1, const float* __restrict__ hb1,
    const float* __restrict__ hw2, const float* __restrict__ hb2,
    const float* __restrict__ ws, float* __restrict__ out)
{
    __shared__ float inbuf[4][128];
    __shared__ float zbuf[4][64];
    const int tid = threadIdx.x;
    const int wv = tid >> 6, lane = tid & 63;
    const int i = blockIdx.x * 4 + wv;

    const float* pm = ws + WS_PM + i*3*64;
    float mi = (pm[lane] + pm[64 + lane] + pm[128 + lane]) * (1.0f / sqrtf(767.0f));
    inbuf[wv][lane] = mi;
    inbuf[wv][64 + lane] = h[i*64 + lane];

    if (lane < 12) {
        const float* ps = ws + WS_PS + i*3*12;
        float sh = ps[lane] + ps[12 + lane] + ps[24 + lane];
        out[i*12 + lane] = x[i*12 + lane] + sh * (1.0f / 767.0f);
    }

    // single wave per node: LDS ops in-order, no barrier needed
    float a = hb0[lane];
    #pragma unroll 8
    for (int k = 0; k < 128; ++k) a += inbuf[wv][k] * hw0[k*64 + lane];
    zbuf[wv][lane] = silu_f(a);

    a = hb1[lane];
    #pragma unroll 8
    for (int k = 0; k < 64; ++k) a += zbuf[wv][k] * hw1[k*64 + lane];
    zbuf[wv][lane] = silu_f(a);

    a = hb2[lane];
    #pragma unroll 8
    for (int k = 0; k < 64; ++k) a += zbuf[wv][k] * hw2[k*64 + lane];
    out[9216 + i*64 + lane] = h[i*64 + lane] + a;
}

extern "C" void kernel_launch(void* const* d_in, const int* in_sizes, int n_in,
                              void* d_out, int out_size, void* d_ws, size_t ws_size,
                              hipStream_t stream) {
    const float* x    = (const float*)d_in[0];
    const float* h    = (const float*)d_in[1];
    const float* ew0  = (const float*)d_in[2];
    const float* eb0  = (const float*)d_in[3];
    const float* ew1  = (const float*)d_in[4];
    const float* eb1  = (const float*)d_in[5];
    const float* infw = (const float*)d_in[6];
    const float* infb = (const float*)d_in[7];
    const float* xw0  = (const float*)d_in[8];
    const float* xb0  = (const float*)d_in[9];
    const float* xw1  = (const float*)d_in[10];
    const float* xb1  = (const float*)d_in[11];
    const float* xw2  = (const float*)d_in[12];
    const float* xb2  = (const float*)d_in[13];
    const float* hw0  = (const float*)d_in[14];
    const float* hb0  = (const float*)d_in[15];
    const float* hw1  = (const float*)d_in[16];
    const float* hb1  = (const float*)d_in[17];
    const float* hw2  = (const float*)d_in[18];
    const float* hb2  = (const float*)d_in[19];

    float* ws  = (float*)d_ws;
    float* out = (float*)d_out;

    prep_kernel<<<200, 256, 0, stream>>>(x, h, ew0, eb0, ew1, eb1, infw, infb,
                                         xw0, xb0, xw1, xb1, xw2, xb2, ws);
    egcl_chunk<<<dim3(3, 768), 256, 0, stream>>>(x, ws);
    finish_kernel<<<192, 256, 0, stream>>>(x, h, hw0, hb0, hw1, hb1, hw2, hb2, ws, out);
}